// Round 7
// baseline (226.388 us; speedup 1.0000x reference)
//
#include <hip/hip_runtime.h>
#include <math.h>
#include <stdint.h>

typedef _Float16 half8 __attribute__((ext_vector_type(8)));
typedef float floatx4 __attribute__((ext_vector_type(4)));

#define NTOK   16384
#define DIM    2048
#define NEXP   64
#define MB     64                  // tokens per block (doubled: halves B bytes/CU)
#define NBLK   (NTOK / MB)         // 256 blocks = exactly 1 per CU
#define KC     32                  // K per chunk (one wsw k-step per chunk)
#define NCHUNK (DIM / KC)          // 64
#define WSW_H8 16384               // half8 slots per split (64 ksteps x 4 tg x 64 lanes)
#define WSW_BYTES (2 * WSW_H8 * 16)

#define A_BYTES 8192               // per ring slot: 64 rows x 128 B
#define B_BYTES 8192               // per ring slot: 2 splits x 4 tg x 1 KB
#define AOFF(b) ((b) * A_BYTES)
#define BOFF(b) (3 * A_BYTES + (b) * B_BYTES)
#define SMEM_BYTES (3 * A_BYTES + 3 * B_BYTES)   // 49152 B static LDS

// ---- prep: split W (fp32) into f16 hi + scaled-lo (2^11), B-fragment order:
// slot(sg,tg,lane) = (sg*4+tg)*64+lane holds W[tg*16+(lane&15)][sg*32+(lane>>4)*8 + 0..7]
__global__ void wprep_kernel(const float* __restrict__ W, _Float16* __restrict__ wsw) {
    const int id   = blockIdx.x * blockDim.x + threadIdx.x; // 0..16383
    const int lane = id & 63;
    const int tg   = (id >> 6) & 3;
    const int sg   = id >> 8;                               // 0..63
    const int e    = tg * 16 + (lane & 15);
    const int k    = sg * 32 + (lane >> 4) * 8;
    const float* src = W + (size_t)e * DIM + k;
    half8 h, l;
#pragma unroll
    for (int j = 0; j < 8; j++) {
        const float v  = src[j];
        const _Float16 hh = (_Float16)v;
        h[j] = hh;
        l[j] = (_Float16)((v - (float)hh) * 2048.0f);
    }
    const size_t slot = (size_t)(sg * 4 + tg) * 64 + lane;
    ((half8*)wsw)[slot]          = h;
    ((half8*)wsw)[WSW_H8 + slot] = l;
}

__device__ __forceinline__ void split_a(const float4& v0, const float4& v1,
                                        half8& hi, half8& lo) {
    const float av[8] = {v0.x, v0.y, v0.z, v0.w, v1.x, v1.y, v1.z, v1.w};
#pragma unroll
    for (int j = 0; j < 8; j++) {
        const _Float16 hh = (_Float16)av[j];
        hi[j] = hh;
        lo[j] = (_Float16)((av[j] - (float)hh) * 2048.0f);
    }
}

// async global->LDS DMA, 16 B/lane. LDS dest = WAVE-UNIFORM base (HW appends lane*16).
__device__ __forceinline__ void dma16(const void* g, const char* l) {
    __builtin_amdgcn_global_load_lds(
        (const __attribute__((address_space(1))) unsigned int*)(uintptr_t)g,
        (__attribute__((address_space(3))) unsigned int*)(uintptr_t)l,
        16, 0, 0);
}

template <int N>
__device__ __forceinline__ void wait_vm() {
    asm volatile("s_waitcnt vmcnt(%0)" :: "n"(N) : "memory");
}

// 64-token block, 8 waves, ring-3, ONE barrier per chunk, counted vmcnt (R6 scheme):
//   iter c: 1. wait vmcnt(OPW)  -> own bundle(c) landed (bundle(c+1) in flight)
//           2. s_barrier        -> all waves' bundle(c) landed; compute(c-1) done
//           3. issue bundle(c+2) into slot (c+2)%3 == (c-1)%3   [safe only here]
//           4. ds_read frags from slot c%3, MFMA
// Per-CU ingress = A 512 KB + B 512 KB = 1.0 MB @ ~10 B/cyc/CU -> ~45 us pacing;
// prefetch distance 2 chunk-times (~3200 cyc) >> HBM latency. Bytes/CU is the
// binding constraint (R0-R6 all paced at their ingress byte count).
template <bool USE_WS>
__global__ __launch_bounds__(512, 2)
void gating_lds_kernel(const float* __restrict__ x, const float* __restrict__ W,
                       const _Float16* __restrict__ wsw, const float* __restrict__ bias,
                       float* __restrict__ out)
{
    __shared__ char smem[SMEM_BYTES];

    const int tid  = threadIdx.x;
    const int lane = tid & 63;
    const int w    = tid >> 6;          // 0..7
    const int mt   = w & 3;             // m-tile (16 tokens each, 4 tiles)
    const int nh   = w >> 2;            // n-half (2 expert tiles of 16)
    const int col  = lane & 15;
    const int quad = lane >> 4;
    const int tok0 = blockIdx.x * MB;
    const int m    = mt * 16 + col;     // this lane's token row (0..63)

    // ---- A DMA source: op a = w covers rows a*8..a*8+7 (128 B each).
    // Gather-side XOR swizzle within 128 B: LDS piece pz holds global piece
    // pz ^ (row&7)  => frag ds_reads land on distinct banks.
    const int arow = w * 8 + (lane >> 3);       // row this lane stages
    const int apz  = lane & 7;                  // LDS piece slot
    const int agp  = apz ^ (arow & 7);          // global piece fetched
    const float* gA = x + (size_t)(tok0 + arow) * DIM + agp * 4;
    const unsigned lA = (unsigned)(w * 1024);
    // ---- B DMA source: op b = w: split = w>>2, tg = w&3 (lane-contiguous copy).
    const half8* gB = nullptr;
    unsigned     lB = 0;
    if constexpr (USE_WS) {
        const int split = w >> 2, tg = w & 3;
        gB = (const half8*)wsw + (size_t)split * WSW_H8 + tg * 64 + lane;
        lB = (unsigned)(split * 4096 + tg * 1024);
    }
    constexpr int OPW = USE_WS ? 2 : 1;   // own DMA ops per bundle

    floatx4 accm[2] = {{0,0,0,0},{0,0,0,0}};
    floatx4 accl[2] = {{0,0,0,0},{0,0,0,0}};

    // prologue: bundles 0 and 1 into slots 0,1
#pragma unroll
    for (int c0 = 0; c0 < 2; c0++) {
        dma16(gA + (size_t)c0 * KC, smem + AOFF(c0) + lA);
        if constexpr (USE_WS)
            dma16(gB + (size_t)c0 * 256, smem + BOFF(c0) + lB);
    }

    int bi = 0, pi = 2;   // read slot (c%3), prefetch slot ((c+2)%3)
    for (int c = 0; c < NCHUNK; ++c) {
        if (c < NCHUNK - 1) wait_vm<OPW>();
        else                wait_vm<0>();
        __builtin_amdgcn_s_barrier();
        asm volatile("" ::: "memory");   // no mem op crosses the barrier

        if (c + 2 < NCHUNK) {            // safe ONLY after the barrier (R4 lesson)
            dma16(gA + (size_t)(c + 2) * KC, smem + AOFF(pi) + lA);
            if constexpr (USE_WS)
                dma16(gB + (size_t)(c + 2) * 256, smem + BOFF(pi) + lB);
        }

        const char* Ab = smem + AOFF(bi);
        const char* Bb = smem + BOFF(bi);
        // A frag: piece (2*quad+j), un-swizzle via ^(m&7)
        const float4 v0 = *(const float4*)(Ab + m * 128 + (((2 * quad + 0) ^ (m & 7))) * 16);
        const float4 v1 = *(const float4*)(Ab + m * 128 + (((2 * quad + 1) ^ (m & 7))) * 16);
        half8 ah, alo;
        split_a(v0, v1, ah, alo);
#pragma unroll
        for (int t = 0; t < 2; t++) {
            const int tg = nh * 2 + t;
            half8 bh, bl;
            if constexpr (USE_WS) {
                bh = *(const half8*)(Bb + tg * 1024 + lane * 16);
                bl = *(const half8*)(Bb + 4096 + tg * 1024 + lane * 16);
            } else {
                const float* wr = W + (size_t)(tg * 16 + col) * DIM + c * KC + quad * 8;
                split_a(*(const float4*)wr, *(const float4*)(wr + 4), bh, bl);
            }
            accm[t] = __builtin_amdgcn_mfma_f32_16x16x32_f16(ah,  bh, accm[t], 0, 0, 0);
            accl[t] = __builtin_amdgcn_mfma_f32_16x16x32_f16(ah,  bl, accl[t], 0, 0, 0);
            accl[t] = __builtin_amdgcn_mfma_f32_16x16x32_f16(alo, bh, accl[t], 0, 0, 0);
        }
        bi = (bi == 2) ? 0 : bi + 1;
        pi = (pi == 2) ? 0 : pi + 1;
    }

    __syncthreads();            // all slot reads done; alias logits onto ring region
    float* lg = (float*)smem;   // [64 tok][65] stride-65 = 16640 B < 49152
    const float inv = 1.0f / 2048.0f;
#pragma unroll
    for (int t = 0; t < 2; t++) {
        const int tg = nh * 2 + t;
#pragma unroll
        for (int r = 0; r < 4; r++) {
            // C/D: row = quad*4+r, col = lane&15  [m89-verified]
            lg[(mt * 16 + quad * 4 + r) * 65 + tg * 16 + col] = accm[t][r] + accl[t][r] * inv;
        }
    }
    __syncthreads();

    if (tid < MB) {
        const int t = tid;
        float v0 = -INFINITY, v1 = -INFINITY;
        int   i0 = 0, i1 = 0;
        for (int e = 0; e < NEXP; e++) {
            const float v = lg[t * 65 + e] + bias[e];
            if (v > v0) { v1 = v0; i1 = i0; v0 = v; i0 = e; }
            else if (v > v1) { v1 = v; i1 = e; }
        }
        const float e1 = expf(v1 - v0);   // v1 <= v0: stable
        const float sden = 1.f + e1;
        const int   g  = tok0 + t;
        out[2 * g + 0] = 1.f / sden;
        out[2 * g + 1] = e1 / sden;
        out[2 * NTOK + 2 * g + 0] = (float)i0;
        out[2 * NTOK + 2 * g + 1] = (float)i1;
    }
}

extern "C" void kernel_launch(void* const* d_in, const int* in_sizes, int n_in,
                              void* d_out, int out_size, void* d_ws, size_t ws_size,
                              hipStream_t stream) {
    const float* x    = (const float*)d_in[0];
    const float* W    = (const float*)d_in[1];
    const float* bias = (const float*)d_in[2];
    float*       out  = (float*)d_out;
    _Float16*    wsw  = (_Float16*)d_ws;

    if (ws_size >= (size_t)WSW_BYTES) {
        hipLaunchKernelGGL(wprep_kernel, dim3(64), dim3(256), 0, stream, W, wsw);
        hipLaunchKernelGGL((gating_lds_kernel<true>), dim3(NBLK), dim3(512), 0, stream,
                           x, W, wsw, bias, out);
    } else {
        hipLaunchKernelGGL((gating_lds_kernel<false>), dim3(NBLK), dim3(512), 0, stream,
                           x, W, wsw, bias, out);
    }
}

// Round 8
// 203.460 us; speedup vs baseline: 1.1127x; 1.1127x over previous
//
#include <hip/hip_runtime.h>
#include <math.h>
#include <stdint.h>

typedef _Float16 half8 __attribute__((ext_vector_type(8)));
typedef float floatx4 __attribute__((ext_vector_type(4)));

#define NTOK 16384
#define DIM  2048
#define NEXP 64
#define MB   64                    // tokens per block
#define NBLK (NTOK / MB)           // 256 blocks = 1 per CU
#define KSPL 8                     // K-split: one slice per wave
#define KW   (DIM / KSPL)          // 256 k per wave
#define NCH  (KW / 32)             // 8 chunks (1 MFMA k-step each)
#define WSW_H8 16384               // half8 slots per split
#define WSW_BYTES (2 * WSW_H8 * 16)

#define SLOT_B  8192               // A slot: 64 rows x 128 B (one 32-k chunk)
#define WAVE_B  (2 * SLOT_B)       // ring-2, wave-private
#define ARING_B (8 * WAVE_B)       // 128 KB; aliased by 8 reduction slabs (8 x 16 KB)
#define FIN_F   (64 * 65)          // final logits, stride-65 (conflict-free scan)

// ---- prep: split W (fp32) into f16 hi + scaled-lo (2^11), B-fragment order:
// slot(sg,tg,lane) = (sg*4+tg)*64+lane holds W[tg*16+(lane&15)][sg*32+(lane>>4)*8 + 0..7]
__global__ void wprep_kernel(const float* __restrict__ W, _Float16* __restrict__ wsw) {
    const int id   = blockIdx.x * blockDim.x + threadIdx.x; // 0..16383
    const int lane = id & 63;
    const int tg   = (id >> 6) & 3;
    const int sg   = id >> 8;                               // 0..63
    const int e    = tg * 16 + (lane & 15);
    const int k    = sg * 32 + (lane >> 4) * 8;
    const float* src = W + (size_t)e * DIM + k;
    half8 h, l;
#pragma unroll
    for (int j = 0; j < 8; j++) {
        const float v  = src[j];
        const _Float16 hh = (_Float16)v;
        h[j] = hh;
        l[j] = (_Float16)((v - (float)hh) * 2048.0f);
    }
    const size_t slot = (size_t)(sg * 4 + tg) * 64 + lane;
    ((half8*)wsw)[slot]          = h;
    ((half8*)wsw)[WSW_H8 + slot] = l;
}

__device__ __forceinline__ void split_a(const float4& v0, const float4& v1,
                                        half8& hi, half8& lo) {
    const float av[8] = {v0.x, v0.y, v0.z, v0.w, v1.x, v1.y, v1.z, v1.w};
#pragma unroll
    for (int j = 0; j < 8; j++) {
        const _Float16 hh = (_Float16)av[j];
        hi[j] = hh;
        lo[j] = (_Float16)((av[j] - (float)hh) * 2048.0f);
    }
}

// async global->LDS DMA, 16 B/lane. LDS dest = WAVE-UNIFORM base (HW appends lane*16).
__device__ __forceinline__ void dma16(const void* g, const char* l) {
    __builtin_amdgcn_global_load_lds(
        (const __attribute__((address_space(1))) unsigned int*)(uintptr_t)g,
        (__attribute__((address_space(3))) unsigned int*)(uintptr_t)l,
        16, 0, 0);
}

template <int N>
__device__ __forceinline__ void wait_vm() {
    asm volatile("s_waitcnt vmcnt(%0)" :: "n"(N) : "memory");
}

// 8-way K-split, BARRIER-FREE k-loop. Wave ks owns 64 tok x 64 exp x k-slice
// [ks*256, ks*256+256). A staged in wave-PRIVATE LDS ring-2 via global_load_lds;
// B fragments loaded straight from wsw (L2-hot, read once per block).
// Per iter c (fences seal order):  [B(c) 8 loads][A-dma(c+1) 8 ops]
//   [wait vmcnt(16): newer-than-A(c) = B(c)8 + A(c+1)8 -> A(c) landed]
//   [ds_read frags slot c&1, 48 MFMA]   (compiler emits its own waits for B regs)
// Chunk = 16 KB/wave; distance-1 prefetch ~ thousands of cycles ahead of use.
// Epilogue: ONE barrier; 8 K-partial slabs alias the A-ring; vector sum; top-2.
template <bool USE_WS>
__global__ __launch_bounds__(512, 2)
void gating_kernel(const float* __restrict__ x, const float* __restrict__ W,
                   const _Float16* __restrict__ wsw, const float* __restrict__ bias,
                   float* __restrict__ out)
{
    __shared__ char  aring[ARING_B];   // 128 KB: k-loop A ring; epilogue: 8 slabs
    __shared__ float fin[FIN_F];       // 16.6 KB
    __shared__ float bsh[NEXP];

    const int tid  = threadIdx.x;
    const int lane = tid & 63;
    const int ks   = tid >> 6;          // 0..7: K-slice (wave id)
    const int col  = lane & 15;
    const int quad = lane >> 4;
    const int tok0 = blockIdx.x * MB;

    if (tid < NEXP) bsh[tid] = bias[tid];

    // A dma: op i covers rows 8i..8i+7 (128 B per row-chunk). XOR piece swizzle:
    // lane: row-in-op = lane>>3, LDS piece pz = lane&7 holds global piece pz^row.
    const int arow = lane >> 3;
    const int agp  = (lane & 7) ^ arow;       // (8i+arow)&7 == arow for all i
    const float* gA = x + (size_t)(tok0 + arow) * DIM + ks * KW + agp * 4;
    char* const wbase = aring + ks * WAVE_B;  // wave-private ring

    floatx4 accm[4][4], accl[4][4];
#pragma unroll
    for (int m = 0; m < 4; m++)
#pragma unroll
        for (int t = 0; t < 4; t++) { accm[m][t] = (floatx4){0,0,0,0}; accl[m][t] = (floatx4){0,0,0,0}; }

    // prologue: chunk 0 -> slot 0
#pragma unroll
    for (int i = 0; i < 8; i++)
        dma16(gA + (size_t)i * 8 * DIM, wbase + i * 1024);

#pragma unroll
    for (int c = 0; c < NCH; ++c) {
        const int sg = ks * NCH + c;          // global k-step 0..63
        half8  bh[4], bl[4];
        float4 bf0[4], bf1[4];
        if constexpr (USE_WS) {
#pragma unroll
            for (int t = 0; t < 4; t++) {
                bh[t] = ((const half8*)wsw)[(size_t)(sg * 4 + t) * 64 + lane];
                bl[t] = ((const half8*)wsw)[WSW_H8 + (size_t)(sg * 4 + t) * 64 + lane];
            }
        } else {
#pragma unroll
            for (int t = 0; t < 4; t++) {
                const float* wr = W + (size_t)(t * 16 + col) * DIM + sg * 32 + quad * 8;
                bf0[t] = *(const float4*)wr;
                bf1[t] = *(const float4*)(wr + 4);
            }
        }
        asm volatile("" ::: "memory");
        if (c + 1 < NCH) {
#pragma unroll
            for (int i = 0; i < 8; i++)
                dma16(gA + (size_t)i * 8 * DIM + (c + 1) * 32,
                      wbase + ((c + 1) & 1) * SLOT_B + i * 1024);
        }
        asm volatile("" ::: "memory");
        if (c + 1 < NCH) wait_vm<16>();   // newer = B(c)8 + A(c+1)8; A(c) landed
        else             wait_vm<8>();    // newer = B(c)8 only
        asm volatile("" ::: "memory");

        const char* Ab = wbase + (c & 1) * SLOT_B;
#pragma unroll
        for (int m = 0; m < 4; m++) {
            const int row = m * 16 + col;
            const float4 v0 = *(const float4*)(Ab + row * 128 + (((2 * quad + 0) ^ (col & 7))) * 16);
            const float4 v1 = *(const float4*)(Ab + row * 128 + (((2 * quad + 1) ^ (col & 7))) * 16);
            half8 ah, al;
            split_a(v0, v1, ah, al);
#pragma unroll
            for (int t = 0; t < 4; t++) {
                half8 hb, lb;
                if constexpr (USE_WS) { hb = bh[t]; lb = bl[t]; }
                else                  { split_a(bf0[t], bf1[t], hb, lb); }
                accm[m][t] = __builtin_amdgcn_mfma_f32_16x16x32_f16(ah, hb, accm[m][t], 0, 0, 0);
                accl[m][t] = __builtin_amdgcn_mfma_f32_16x16x32_f16(ah, lb, accl[m][t], 0, 0, 0);
                accl[m][t] = __builtin_amdgcn_mfma_f32_16x16x32_f16(al, hb, accl[m][t], 0, 0, 0);
            }
        }
    }

    __syncthreads();      // single sync: all waves done with A-ring; alias slabs
    {   // wave ks writes its 64x64 K-partial into slab ks
        float* slab = (float*)(aring + ks * 16384);
        const float inv = 1.0f / 2048.0f;
#pragma unroll
        for (int m = 0; m < 4; m++)
#pragma unroll
            for (int t = 0; t < 4; t++)
#pragma unroll
                for (int r = 0; r < 4; r++)   // C/D: row=quad*4+r, col=lane&15 [m89]
                    slab[(m * 16 + quad * 4 + r) * 64 + t * 16 + col] =
                        accm[m][t][r] + accl[m][t][r] * inv;
    }
    __syncthreads();
    {   // 512 threads: sum 8 slabs + bias -> fin[64][65]
        const int tk = tid >> 3;
        const int e0 = (tid & 7) * 8;
        floatx4 s0 = {0,0,0,0}, s1 = {0,0,0,0};
#pragma unroll
        for (int p = 0; p < KSPL; p++) {
            const float* sb = (const float*)(aring + p * 16384) + tk * 64 + e0;
            s0 += *(const floatx4*)sb;
            s1 += *(const floatx4*)(sb + 4);
        }
#pragma unroll
        for (int j = 0; j < 4; j++) {
            fin[tk * 65 + e0 + j]     = s0[j] + bsh[e0 + j];
            fin[tk * 65 + e0 + 4 + j] = s1[j] + bsh[e0 + 4 + j];
        }
    }
    __syncthreads();

    if (tid < MB) {
        const int tk = tid;
        float v0 = -INFINITY, v1 = -INFINITY;
        int   i0 = 0, i1 = 0;
        for (int e = 0; e < NEXP; e++) {
            const float v = fin[tk * 65 + e];
            if (v > v0)      { v1 = v0; i1 = i0; v0 = v; i0 = e; }
            else if (v > v1) { v1 = v; i1 = e; }
        }
        const float e1 = expf(v1 - v0);   // v1 <= v0: stable
        const float sden = 1.f + e1;
        const int   g  = tok0 + tk;
        out[2 * g + 0] = 1.f / sden;
        out[2 * g + 1] = e1 / sden;
        out[2 * NTOK + 2 * g + 0] = (float)i0;
        out[2 * NTOK + 2 * g + 1] = (float)i1;
    }
}

extern "C" void kernel_launch(void* const* d_in, const int* in_sizes, int n_in,
                              void* d_out, int out_size, void* d_ws, size_t ws_size,
                              hipStream_t stream) {
    const float* x    = (const float*)d_in[0];
    const float* W    = (const float*)d_in[1];
    const float* bias = (const float*)d_in[2];
    float*       out  = (float*)d_out;
    _Float16*    wsw  = (_Float16*)d_ws;

    if (ws_size >= (size_t)WSW_BYTES) {
        hipLaunchKernelGGL(wprep_kernel, dim3(64), dim3(256), 0, stream, W, wsw);
        hipLaunchKernelGGL((gating_kernel<true>), dim3(NBLK), dim3(512), 0, stream,
                           x, W, wsw, bias, out);
    } else {
        hipLaunchKernelGGL((gating_kernel<false>), dim3(NBLK), dim3(512), 0, stream,
                           x, W, nullptr, bias, out);
    }
}